// Round 1
// baseline (276.797 us; speedup 1.0000x reference)
//
#include <hip/hip_runtime.h>

#define BATCH  32
#define W_GRID 640
#define H_GRID 480
#define IMG_H  480
#define IMG_W  640
#define TOTAL  (BATCH * W_GRID * H_GRID)

// order-preserving float <-> unsigned key for atomicMax on floats (any sign)
__device__ __forceinline__ unsigned f2key(float f) {
    unsigned u = __float_as_uint(f);
    return (u & 0x80000000u) ? ~u : (u | 0x80000000u);
}
__device__ __forceinline__ float key2f(unsigned k) {
    unsigned u = (k & 0x80000000u) ? (k & 0x7fffffffu) : ~k;
    return __uint_as_float(u);
}

// general 3x3 inverse (adjugate/det), row-major
__device__ __forceinline__ void kinv3(const float* __restrict__ K, float* Ki) {
    float a = K[0], b = K[1], c = K[2];
    float d = K[3], e = K[4], f = K[5];
    float g = K[6], h = K[7], i = K[8];
    float C00 =  (e * i - f * h);
    float C01 = -(d * i - f * g);
    float C02 =  (d * h - e * g);
    float det = a * C00 + b * C01 + c * C02;
    float r = 1.0f / det;
    Ki[0] = C00 * r;            // inv[0][0]
    Ki[1] = -(b * i - c * h) * r; // inv[0][1] = C10
    Ki[2] =  (b * f - c * e) * r; // inv[0][2] = C20
    Ki[3] = C01 * r;            // inv[1][0]
    Ki[4] =  (a * i - c * g) * r; // inv[1][1] = C11
    Ki[5] = -(a * f - c * d) * r; // inv[1][2] = C21
    Ki[6] = C02 * r;            // inv[2][0]
    Ki[7] = -(a * h - b * g) * r; // inv[2][1] = C12
    Ki[8] =  (a * e - b * d) * r; // inv[2][2] = C22
}

// uv for pixel (b, w, h): homo_uv = (h, w, 1) per the reference's meshgrid quirk
__device__ __forceinline__ void compute_uv(int b, int w, int h, float d,
                                           const float* __restrict__ T,
                                           const float* __restrict__ K,
                                           const float* Ki,
                                           float& u, float& v) {
    float hh = (float)h, ww = (float)w;
    // q = (h, w, 1) @ K_inv  (row-vector)
    float q0 = hh * Ki[0] + ww * Ki[3] + Ki[6];
    float q1 = hh * Ki[1] + ww * Ki[4] + Ki[7];
    float q2 = hh * Ki[2] + ww * Ki[5] + Ki[8];
    // p = d*q;  tr = (p,1) @ T, first 3 comps
    const float* Tb = T + b * 16;
    float tr0 = d * (q0 * Tb[0] + q1 * Tb[4] + q2 * Tb[8])  + Tb[12];
    float tr1 = d * (q0 * Tb[1] + q1 * Tb[5] + q2 * Tb[9])  + Tb[13];
    float tr2 = d * (q0 * Tb[2] + q1 * Tb[6] + q2 * Tb[10]) + Tb[14];
    // dir = tr @ K (row-vector)
    float dir0 = tr0 * K[0] + tr1 * K[3] + tr2 * K[6];
    float dir1 = tr0 * K[1] + tr1 * K[4] + tr2 * K[7];
    float dir2 = tr0 * K[2] + tr1 * K[5] + tr2 * K[8];
    float inv = 1.0f / (dir2 + 1e-4f);
    u = dir0 * inv;
    v = dir1 * inv;
}

__global__ void __launch_bounds__(256) uv_max_kernel(
    const float* __restrict__ depth, const float* __restrict__ T,
    const float* __restrict__ K, unsigned* __restrict__ maxkey)
{
    float Ki[9];
    kinv3(K, Ki);
    float lmax = -3.4e38f;
    int stride = gridDim.x * blockDim.x;
    for (int i = blockIdx.x * blockDim.x + threadIdx.x; i < TOTAL; i += stride) {
        int h = i % H_GRID;
        int t = i / H_GRID;
        int w = t % W_GRID;
        int b = t / W_GRID;
        float u, v;
        compute_uv(b, w, h, depth[i], T, K, Ki, u, v);
        lmax = fmaxf(lmax, fmaxf(u, v));
    }
    // wave64 reduce
    for (int off = 32; off > 0; off >>= 1)
        lmax = fmaxf(lmax, __shfl_down(lmax, off, 64));
    __shared__ float sm[4];
    int lane = threadIdx.x & 63, wid = threadIdx.x >> 6;
    if (lane == 0) sm[wid] = lmax;
    __syncthreads();
    if (threadIdx.x == 0) {
        float bm = fmaxf(fmaxf(sm[0], sm[1]), fmaxf(sm[2], sm[3]));
        atomicMax(maxkey, f2key(bm));
    }
}

__global__ void __launch_bounds__(256) sample_kernel(
    const float* __restrict__ depth, const float* __restrict__ T,
    const float* __restrict__ K, const float* __restrict__ img,
    const unsigned* __restrict__ maxkey, float* __restrict__ out)
{
    int i = blockIdx.x * blockDim.x + threadIdx.x;
    if (i >= TOTAL) return;
    float Ki[9];
    kinv3(K, Ki);
    int h = i % H_GRID;
    int t = i / H_GRID;
    int w = t % W_GRID;
    int b = t / W_GRID;
    float u, v;
    compute_uv(b, w, h, depth[i], T, K, Ki, u, v);

    float m = key2f(*maxkey);
    float gu = 2.0f * (u / m) - 1.0f;
    float gv = 2.0f * (v / m) - 1.0f;

    // torch grid_sample bilinear, zeros padding, align_corners=False
    float x = (gu + 1.0f) * (IMG_W * 0.5f) - 0.5f;
    float y = (gv + 1.0f) * (IMG_H * 0.5f) - 0.5f;
    float x0f = floorf(x), y0f = floorf(y);
    float wx = x - x0f, wy = y - y0f;

    bool vx0 = (x0f >= 0.0f) && (x0f <= (float)(IMG_W - 1));
    bool vx1 = (x0f + 1.0f >= 0.0f) && (x0f + 1.0f <= (float)(IMG_W - 1));
    bool vy0 = (y0f >= 0.0f) && (y0f <= (float)(IMG_H - 1));
    bool vy1 = (y0f + 1.0f >= 0.0f) && (y0f + 1.0f <= (float)(IMG_H - 1));

    int xi0 = (int)fminf(fmaxf(x0f, 0.0f), (float)(IMG_W - 1));
    int xi1 = (int)fminf(fmaxf(x0f + 1.0f, 0.0f), (float)(IMG_W - 1));
    int yi0 = (int)fminf(fmaxf(y0f, 0.0f), (float)(IMG_H - 1));
    int yi1 = (int)fminf(fmaxf(y0f + 1.0f, 0.0f), (float)(IMG_H - 1));

    float w00 = (1.0f - wx) * (1.0f - wy);
    float w01 = wx * (1.0f - wy);
    float w10 = (1.0f - wx) * wy;
    float w11 = wx * wy;

    #pragma unroll
    for (int c = 0; c < 3; c++) {
        const float* plane = img + ((size_t)(b * 3 + c)) * IMG_H * IMG_W;
        float v00 = (vx0 && vy0) ? plane[yi0 * IMG_W + xi0] : 0.0f;
        float v01 = (vx1 && vy0) ? plane[yi0 * IMG_W + xi1] : 0.0f;
        float v10 = (vx0 && vy1) ? plane[yi1 * IMG_W + xi0] : 0.0f;
        float v11 = (vx1 && vy1) ? plane[yi1 * IMG_W + xi1] : 0.0f;
        out[(((size_t)(b * 3 + c)) * W_GRID + w) * H_GRID + h] =
            v00 * w00 + v01 * w01 + v10 * w10 + v11 * w11;
    }
}

extern "C" void kernel_launch(void* const* d_in, const int* in_sizes, int n_in,
                              void* d_out, int out_size, void* d_ws, size_t ws_size,
                              hipStream_t stream) {
    const float* depth = (const float*)d_in[0];  // [32,640,480,1]
    const float* T     = (const float*)d_in[1];  // [32,4,4]
    const float* img   = (const float*)d_in[2];  // [32,3,480,640]
    const float* K     = (const float*)d_in[3];  // [3,3]
    float* out = (float*)d_out;                  // [32,3,640,480]
    unsigned* maxkey = (unsigned*)d_ws;

    hipMemsetAsync(maxkey, 0, sizeof(unsigned), stream);
    uv_max_kernel<<<2048, 256, 0, stream>>>(depth, T, K, maxkey);
    sample_kernel<<<(TOTAL + 255) / 256, 256, 0, stream>>>(depth, T, K, img, maxkey, out);
}

// Round 2
// 234.111 us; speedup vs baseline: 1.1823x; 1.1823x over previous
//
#include <hip/hip_runtime.h>

#define BATCH  32
#define W_GRID 640
#define H_GRID 480
#define IMG_H  480
#define IMG_W  640
#define TOTAL  (BATCH * W_GRID * H_GRID)
#define NG     (TOTAL / 4)          // groups of 4 consecutive h
#define H4     (H_GRID / 4)         // 120

// order-preserving float <-> unsigned key for atomicMax on floats (any sign)
__device__ __forceinline__ unsigned f2key(float f) {
    unsigned u = __float_as_uint(f);
    return (u & 0x80000000u) ? ~u : (u | 0x80000000u);
}
__device__ __forceinline__ float key2f(unsigned k) {
    unsigned u = (k & 0x80000000u) ? (k & 0x7fffffffu) : ~k;
    return __uint_as_float(u);
}

// general 3x3 inverse (adjugate/det), row-major
__device__ __forceinline__ void kinv3(const float* __restrict__ K, float* Ki) {
    float a = K[0], b = K[1], c = K[2];
    float d = K[3], e = K[4], f = K[5];
    float g = K[6], h = K[7], i = K[8];
    float C00 =  (e * i - f * h);
    float C01 = -(d * i - f * g);
    float C02 =  (d * h - e * g);
    float det = a * C00 + b * C01 + c * C02;
    float r = 1.0f / det;
    Ki[0] = C00 * r;
    Ki[1] = -(b * i - c * h) * r;
    Ki[2] =  (b * f - c * e) * r;
    Ki[3] = C01 * r;
    Ki[4] =  (a * i - c * g) * r;
    Ki[5] = -(a * f - c * d) * r;
    Ki[6] = C02 * r;
    Ki[7] = -(a * h - b * g) * r;
    Ki[8] =  (a * e - b * d) * r;
}

// uv for pixel with homo_uv = (h, w, 1); Tb = 16 transform floats in registers
__device__ __forceinline__ void uv_from(float hh, float ww, float d,
                                        const float* Ki, const float* __restrict__ K,
                                        const float* Tb, float& u, float& v) {
    float q0 = hh * Ki[0] + ww * Ki[3] + Ki[6];
    float q1 = hh * Ki[1] + ww * Ki[4] + Ki[7];
    float q2 = hh * Ki[2] + ww * Ki[5] + Ki[8];
    float tr0 = d * (q0 * Tb[0] + q1 * Tb[4] + q2 * Tb[8])  + Tb[12];
    float tr1 = d * (q0 * Tb[1] + q1 * Tb[5] + q2 * Tb[9])  + Tb[13];
    float tr2 = d * (q0 * Tb[2] + q1 * Tb[6] + q2 * Tb[10]) + Tb[14];
    float dir0 = tr0 * K[0] + tr1 * K[3] + tr2 * K[6];
    float dir1 = tr0 * K[1] + tr1 * K[4] + tr2 * K[7];
    float dir2 = tr0 * K[2] + tr1 * K[5] + tr2 * K[8];
    float inv = 1.0f / (dir2 + 1e-4f);
    u = dir0 * inv;
    v = dir1 * inv;
}

__device__ __forceinline__ void load_T16(const float* __restrict__ T, int b, float* Tb) {
    const float4* t4 = (const float4*)(T + b * 16);
    #pragma unroll
    for (int k = 0; k < 4; k++) {
        float4 r = t4[k];
        Tb[k * 4 + 0] = r.x; Tb[k * 4 + 1] = r.y;
        Tb[k * 4 + 2] = r.z; Tb[k * 4 + 3] = r.w;
    }
}

__global__ void __launch_bounds__(256) uv_max_kernel(
    const float* __restrict__ depth, const float* __restrict__ T,
    const float* __restrict__ K, unsigned* __restrict__ maxkey)
{
    float Ki[9];
    kinv3(K, Ki);
    const float4* d4 = (const float4*)depth;
    float lmax = -3.4e38f;
    int stride = gridDim.x * blockDim.x;
    for (int g = blockIdx.x * blockDim.x + threadIdx.x; g < NG; g += stride) {
        int h4 = g % H4;
        int t  = g / H4;
        int w  = t % W_GRID;
        int b  = t / W_GRID;
        float4 dv = d4[g];
        float dd[4] = {dv.x, dv.y, dv.z, dv.w};
        float Tb[16];
        load_T16(T, b, Tb);
        float hh = (float)(h4 * 4), ww = (float)w;
        #pragma unroll
        for (int j = 0; j < 4; j++) {
            float u, v;
            uv_from(hh + (float)j, ww, dd[j], Ki, K, Tb, u, v);
            lmax = fmaxf(lmax, fmaxf(u, v));
        }
    }
    #pragma unroll
    for (int off = 32; off > 0; off >>= 1)
        lmax = fmaxf(lmax, __shfl_down(lmax, off, 64));
    __shared__ float sm[4];
    int lane = threadIdx.x & 63, wid = threadIdx.x >> 6;
    if (lane == 0) sm[wid] = lmax;
    __syncthreads();
    if (threadIdx.x == 0) {
        float bm = fmaxf(fmaxf(sm[0], sm[1]), fmaxf(sm[2], sm[3]));
        atomicMax(maxkey, f2key(bm));
    }
}

__global__ void __launch_bounds__(256) sample_kernel(
    const float* __restrict__ depth, const float* __restrict__ T,
    const float* __restrict__ K, const float* __restrict__ img,
    const unsigned* __restrict__ maxkey, float* __restrict__ out)
{
    int g = blockIdx.x * blockDim.x + threadIdx.x;
    if (g >= NG) return;
    float Ki[9];
    kinv3(K, Ki);
    int h4 = g % H4;
    int t  = g / H4;
    int w  = t % W_GRID;
    int b  = t / W_GRID;
    const float4* d4 = (const float4*)depth;
    float4 dv = d4[g];
    float dd[4] = {dv.x, dv.y, dv.z, dv.w};
    float Tb[16];
    load_T16(T, b, Tb);

    float m = key2f(*maxkey);
    // x = (2*(u/m) - 1 + 1) * W/2 - 0.5 = u * (W/m) - 0.5  (same for y with H)
    float sx = (float)IMG_W / m;
    float sy = (float)IMG_H / m;

    float acc[3][4];
    float hh = (float)(h4 * 4), ww = (float)w;

    #pragma unroll
    for (int j = 0; j < 4; j++) {
        float u, v;
        uv_from(hh + (float)j, ww, dd[j], Ki, K, Tb, u, v);
        float x = u * sx - 0.5f;
        float y = v * sy - 0.5f;
        float x0f = floorf(x), y0f = floorf(y);
        float wx = x - x0f, wy = y - y0f;

        bool vx0 = (x0f >= 0.0f) && (x0f <= (float)(IMG_W - 1));
        bool vx1 = (x0f + 1.0f >= 0.0f) && (x0f + 1.0f <= (float)(IMG_W - 1));
        bool vy0 = (y0f >= 0.0f) && (y0f <= (float)(IMG_H - 1));
        bool vy1 = (y0f + 1.0f >= 0.0f) && (y0f + 1.0f <= (float)(IMG_H - 1));

        int xi0 = (int)fminf(fmaxf(x0f, 0.0f), (float)(IMG_W - 1));
        int xi1 = (int)fminf(fmaxf(x0f + 1.0f, 0.0f), (float)(IMG_W - 1));
        int yi0 = (int)fminf(fmaxf(y0f, 0.0f), (float)(IMG_H - 1));
        int yi1 = (int)fminf(fmaxf(y0f + 1.0f, 0.0f), (float)(IMG_H - 1));

        float w00 = (1.0f - wx) * (1.0f - wy);
        float w01 = wx * (1.0f - wy);
        float w10 = (1.0f - wx) * wy;
        float w11 = wx * wy;

        #pragma unroll
        for (int c = 0; c < 3; c++) {
            const float* plane = img + ((size_t)(b * 3 + c)) * IMG_H * IMG_W;
            float v00 = (vx0 && vy0) ? plane[yi0 * IMG_W + xi0] : 0.0f;
            float v01 = (vx1 && vy0) ? plane[yi0 * IMG_W + xi1] : 0.0f;
            float v10 = (vx0 && vy1) ? plane[yi1 * IMG_W + xi0] : 0.0f;
            float v11 = (vx1 && vy1) ? plane[yi1 * IMG_W + xi1] : 0.0f;
            acc[c][j] = v00 * w00 + v01 * w01 + v10 * w10 + v11 * w11;
        }
    }

    #pragma unroll
    for (int c = 0; c < 3; c++) {
        float4* dst = (float4*)(out + (((size_t)(b * 3 + c)) * W_GRID + w) * H_GRID + h4 * 4);
        *dst = make_float4(acc[c][0], acc[c][1], acc[c][2], acc[c][3]);
    }
}

extern "C" void kernel_launch(void* const* d_in, const int* in_sizes, int n_in,
                              void* d_out, int out_size, void* d_ws, size_t ws_size,
                              hipStream_t stream) {
    const float* depth = (const float*)d_in[0];  // [32,640,480,1]
    const float* T     = (const float*)d_in[1];  // [32,4,4]
    const float* img   = (const float*)d_in[2];  // [32,3,480,640]
    const float* K     = (const float*)d_in[3];  // [3,3]
    float* out = (float*)d_out;                  // [32,3,640,480]
    unsigned* maxkey = (unsigned*)d_ws;

    hipMemsetAsync(maxkey, 0, sizeof(unsigned), stream);
    uv_max_kernel<<<1024, 256, 0, stream>>>(depth, T, K, maxkey);
    sample_kernel<<<NG / 256, 256, 0, stream>>>(depth, T, K, img, maxkey, out);
}